// Round 1
// baseline (99.261 us; speedup 1.0000x reference)
//
#include <hip/hip_runtime.h>

// Problem constants (fixed by reference setup_inputs)
constexpr int B = 16, H = 1024, W = 1024, N = 2000;
constexpr int HW = H * W;                       // 1,048,576
constexpr long long TOT = (long long)B * HW;    // 16,777,216
constexpr float SMOOTH = 1e-6f;

typedef float f32x4 __attribute__((ext_vector_type(4)));
typedef unsigned int u32x4 __attribute__((ext_vector_type(4)));

// Workspace layout:
//   [0, 2MB)                 : gt bitmask (uint32 words)
//   [2MB, 2MB+48KB)          : per-block partials part[q*NBLOCKS + blk], q=0..5
//   [2MB+48KB, +4B)          : arrival counter for last-block finalize
constexpr size_t MASK_WORDS = (size_t)B * HW / 32;   // 524,288 words
constexpr size_t MASK_BYTES = MASK_WORDS * 4;        // 2 MB

constexpr int BLOCKS_PER_BATCH = 128;
constexpr int NBLOCKS = B * BLOCKS_PER_BATCH;        // 2048
constexpr int THREADS = 256;
constexpr int UNROLL = 8;
constexpr int PART_FLOATS = 6 * NBLOCKS;             // 12,288 floats (48 KB)

// ---------------------------------------------------------------------------
// Zero the mask + arrival counter. 512 blocks x 256 threads x 16B = 2 MB.
// Replaces hipMemsetAsync's rocclr fill, which profiled at 51.8 GB/s / 40.6us.
// ---------------------------------------------------------------------------
__global__ __launch_bounds__(256)
void zero_kernel(u32x4* __restrict__ maskv, unsigned int* __restrict__ ctr) {
    int t = blockIdx.x * 256 + threadIdx.x;
    maskv[t] = (u32x4)(0u);
    if (t == 0) *ctr = 0u;   // visible to next kernel via kernel-boundary release
}

__global__ __launch_bounds__(256)
void raster_kernel(const int* __restrict__ pts,
                   unsigned int* __restrict__ mask) {
    int t = blockIdx.x * blockDim.x + threadIdx.x;
    if (t >= B * N) return;
    int b = t / N;
    int x = pts[2 * t + 0];
    int y = pts[2 * t + 1];
    int cx = x >> 2;   // floor div 4
    int cy = y >> 2;
    if (cx < 0 || cx >= W || cy < 0 || cy >= H) return;
    const int dy[13] = {-2, -1, -1, -1,  0, 0, 0, 0, 0,  1, 1, 1,  2};
    const int dx[13] = { 0, -1,  0,  1, -2,-1, 0, 1, 2, -1, 0, 1,  0};
    unsigned int base = (unsigned int)b * HW;
#pragma unroll
    for (int k = 0; k < 13; ++k) {
        int yy = cy + dy[k];
        int xx = cx + dx[k];
        if (yy >= 0 && yy < H && xx >= 0 && xx < W) {
            unsigned int idx = base + (unsigned int)yy * W + (unsigned int)xx;
            atomicOr(&mask[idx >> 5], 1u << (idx & 31));
        }
    }
}

__device__ inline float wave_reduce(float v) {
#pragma unroll
    for (int o = 32; o > 0; o >>= 1) v += __shfl_down(v, o, 64);
    return v;
}

// ---------------------------------------------------------------------------
// Main pass + fused finalize (last arriving block does the reduction).
// Cross-XCD visibility: partials stored/loaded with agent-scope atomics;
// the acq_rel fetch_add on ctr orders every block's release before the last
// block's acquire. No extra dispatch for reduce_finalize.
// ---------------------------------------------------------------------------
__global__ __launch_bounds__(THREADS)
void mainpass_kernel(const float* __restrict__ logits,
                     const unsigned int* __restrict__ mask,
                     float* __restrict__ part,
                     unsigned int* __restrict__ ctr,
                     float* __restrict__ out) {
    const int blk = blockIdx.x;
    const int b = blk / BLOCKS_PER_BATCH;
    const int chunk = blk % BLOCKS_PER_BATCH;
    const int base_v = b * (HW / 4) + chunk * (UNROLL * THREADS);
    const int tid = threadIdx.x;

    const f32x4* __restrict__ vlog = reinterpret_cast<const f32x4*>(logits);

    f32x4 xv[UNROLL];
    unsigned int mw[UNROLL];
#pragma unroll
    for (int it = 0; it < UNROLL; ++it) {
        int v = base_v + it * THREADS + tid;
        xv[it] = vlog[v];
        mw[it] = mask[(unsigned int)v >> 3];
    }

    float sA = 0.f, sBg = 0.f, sCg = 0.f, si = 0.f, spr = 0.f, sg = 0.f;

#pragma unroll
    for (int it = 0; it < UNROLL; ++it) {
        int v = base_v + it * THREADS + tid;
        unsigned int bits = mw[it] >> ((v & 7) * 4);   // low 4 bits valid
#pragma unroll
        for (int j = 0; j < 4; ++j) {
            float x = xv[it][j];
            float g = (float)((bits >> j) & 1u);
            float ax = fabsf(x);
            float t = __builtin_amdgcn_exp2f(-1.44269504f * ax);  // e^-|x|
            float u = 1.0f + t;
            float l = __builtin_amdgcn_logf(u) * 0.69314718f;     // log(1+t)
            float sp = l + fmaxf(x, 0.f);                         // softplus(x)
            float r = __builtin_amdgcn_rcpf(u);
            float prob = r * ((x >= 0.f) ? 1.0f : t);             // sigmoid(x)
            sA += sp;
            sBg += g * sp;
            sCg += g * x;
            si += g * prob;
            spr += prob;
            sg += g;
        }
    }

    __shared__ float red[4][6];
    const int lane = tid & 63;
    const int wv = tid >> 6;
    sA = wave_reduce(sA);
    sBg = wave_reduce(sBg);
    sCg = wave_reduce(sCg);
    si = wave_reduce(si);
    spr = wave_reduce(spr);
    sg = wave_reduce(sg);
    if (lane == 0) {
        red[wv][0] = sA; red[wv][1] = sBg; red[wv][2] = sCg;
        red[wv][3] = si; red[wv][4] = spr; red[wv][5] = sg;
    }
    __syncthreads();

    __shared__ int slast;
    if (tid == 0) {
        float a[6] = {0, 0, 0, 0, 0, 0};
#pragma unroll
        for (int w = 0; w < 4; ++w)
#pragma unroll
            for (int q = 0; q < 6; ++q) a[q] += red[w][q];
        // Agent-scope stores so the last block (possibly on another XCD) sees them.
#pragma unroll
        for (int q = 0; q < 6; ++q)
            __hip_atomic_store(&part[q * NBLOCKS + blk], a[q],
                               __ATOMIC_RELAXED, __HIP_MEMORY_SCOPE_AGENT);
        unsigned int old = __hip_atomic_fetch_add(ctr, 1u, __ATOMIC_ACQ_REL,
                                                  __HIP_MEMORY_SCOPE_AGENT);
        slast = (old == (unsigned int)(NBLOCKS - 1)) ? 1 : 0;
    }
    __syncthreads();
    if (!slast) return;

    // ---- last block: finalize (same math as the old reduce kernel) ----

    // global sums (q = 0,1,2)
    float a0 = 0.f, a1 = 0.f, a2 = 0.f;
#pragma unroll
    for (int k = 0; k < NBLOCKS / 256; ++k) {
        int i = tid + 256 * k;
        a0 += __hip_atomic_load(&part[0 * NBLOCKS + i], __ATOMIC_RELAXED,
                                __HIP_MEMORY_SCOPE_AGENT);
        a1 += __hip_atomic_load(&part[1 * NBLOCKS + i], __ATOMIC_RELAXED,
                                __HIP_MEMORY_SCOPE_AGENT);
        a2 += __hip_atomic_load(&part[2 * NBLOCKS + i], __ATOMIC_RELAXED,
                                __HIP_MEMORY_SCOPE_AGENT);
    }
    a0 = wave_reduce(a0);
    a1 = wave_reduce(a1);
    a2 = wave_reduce(a2);
    __shared__ float redg[4][3];
    if (lane == 0) { redg[wv][0] = a0; redg[wv][1] = a1; redg[wv][2] = a2; }

    // per-batch sums (q = 3,4,5): 16 threads per batch
    int bb = tid >> 4;       // 0..15
    int j = tid & 15;        // 0..15
    float p3 = 0.f, p4 = 0.f, p5 = 0.f;
#pragma unroll
    for (int k = 0; k < BLOCKS_PER_BATCH / 16; ++k) {
        int idx = bb * BLOCKS_PER_BATCH + j + 16 * k;
        p3 += __hip_atomic_load(&part[3 * NBLOCKS + idx], __ATOMIC_RELAXED,
                                __HIP_MEMORY_SCOPE_AGENT);
        p4 += __hip_atomic_load(&part[4 * NBLOCKS + idx], __ATOMIC_RELAXED,
                                __HIP_MEMORY_SCOPE_AGENT);
        p5 += __hip_atomic_load(&part[5 * NBLOCKS + idx], __ATOMIC_RELAXED,
                                __HIP_MEMORY_SCOPE_AGENT);
    }
#pragma unroll
    for (int m = 1; m < 16; m <<= 1) {
        p3 += __shfl_xor(p3, m, 64);
        p4 += __shfl_xor(p4, m, 64);
        p5 += __shfl_xor(p5, m, 64);
    }
    __shared__ float sI[16], sP[16], sG[16];
    if (j == 0) { sI[bb] = p3; sP[bb] = p4; sG[bb] = p5; }
    __syncthreads();

    if (tid == 0) {
        float A = 0.f, Bg = 0.f, Cg = 0.f;
#pragma unroll
        for (int w = 0; w < 4; ++w) {
            A += redg[w][0]; Bg += redg[w][1]; Cg += redg[w][2];
        }
        float S1 = Bg - Cg;          // sum g*softplus(-x)
        float S2 = A - Bg;           // sum (1-g)*softplus(x)
        float pos = 0.f;
#pragma unroll
        for (int k = 0; k < B; ++k) pos += sG[k];
        float neg = (float)TOT - pos;
        float pw = neg / (pos + SMOOTH);
        float bce = (pw * S1 + S2) / (float)TOT;
        float dsum = 0.f;
#pragma unroll
        for (int k = 0; k < B; ++k) {
            dsum += (2.f * sI[k] + SMOOTH) / (sP[k] + sG[k] + SMOOTH);
        }
        float dice = 1.f - dsum / (float)B;
        out[0] = 0.5f * bce + 0.5f * dice;
    }
}

extern "C" void kernel_launch(void* const* d_in, const int* in_sizes, int n_in,
                              void* d_out, int out_size, void* d_ws, size_t ws_size,
                              hipStream_t stream) {
    const float* logits = (const float*)d_in[0];
    const int* pts = (const int*)d_in[1];
    unsigned int* mask = (unsigned int*)d_ws;
    float* part = (float*)((char*)d_ws + MASK_BYTES);
    unsigned int* ctr = (unsigned int*)((char*)d_ws + MASK_BYTES +
                                        (size_t)PART_FLOATS * 4);

    // Custom wide zero of mask + counter (no hipMemsetAsync / rocclr fill).
    zero_kernel<<<(int)(MASK_WORDS / 4 / 256), 256, 0, stream>>>(
        reinterpret_cast<u32x4*>(mask), ctr);

    raster_kernel<<<(B * N + 255) / 256, 256, 0, stream>>>(pts, mask);

    mainpass_kernel<<<NBLOCKS, THREADS, 0, stream>>>(logits, mask, part, ctr,
                                                     (float*)d_out);
}

// Round 2
// 47.763 us; speedup vs baseline: 2.0782x; 2.0782x over previous
//
#include <hip/hip_runtime.h>

// Problem constants (fixed by reference setup_inputs)
constexpr int B = 16, H = 1024, W = 1024, N = 2000;
constexpr int HW = H * W;                       // 1,048,576
constexpr long long TOT = (long long)B * HW;    // 16,777,216
constexpr float SMOOTH = 1e-6f;

typedef float f32x4 __attribute__((ext_vector_type(4)));
typedef unsigned int u32x4 __attribute__((ext_vector_type(4)));

// Workspace layout:
//   [0, 2MB)            : gt bitmask (uint32 words)
//   [2MB, 2MB+48KB)     : per-block partials part[q*NBLOCKS + blk], q=0..5
constexpr size_t MASK_WORDS = (size_t)B * HW / 32;   // 524,288 words
constexpr size_t MASK_BYTES = MASK_WORDS * 4;        // 2 MB

constexpr int BLOCKS_PER_BATCH = 128;
constexpr int NBLOCKS = B * BLOCKS_PER_BATCH;        // 2048
constexpr int THREADS = 256;
constexpr int UNROLL = 8;

// ---------------------------------------------------------------------------
// Zero the mask. 512 blocks x 256 threads x 16B = 2 MB.
// Replaces hipMemsetAsync's rocclr fill (profiled 51.8 GB/s / 40.6 us).
// NOTE (round 1 lesson): do NOT fuse finalize into mainpass via agent-scope
// atomics — on gfx950 the cross-XCD coherence ops (L2 wb/inv per block) made
// mainpass 14x slower. Kernel-boundary handoff is cheaper.
// ---------------------------------------------------------------------------
__global__ __launch_bounds__(256)
void zero_kernel(u32x4* __restrict__ maskv) {
    int t = blockIdx.x * 256 + threadIdx.x;
    maskv[t] = (u32x4)(0u);
}

__global__ __launch_bounds__(256)
void raster_kernel(const int* __restrict__ pts,
                   unsigned int* __restrict__ mask) {
    int t = blockIdx.x * blockDim.x + threadIdx.x;
    if (t >= B * N) return;
    int b = t / N;
    int x = pts[2 * t + 0];
    int y = pts[2 * t + 1];
    int cx = x >> 2;   // floor div 4
    int cy = y >> 2;
    if (cx < 0 || cx >= W || cy < 0 || cy >= H) return;
    const int dy[13] = {-2, -1, -1, -1,  0, 0, 0, 0, 0,  1, 1, 1,  2};
    const int dx[13] = { 0, -1,  0,  1, -2,-1, 0, 1, 2, -1, 0, 1,  0};
    unsigned int base = (unsigned int)b * HW;
#pragma unroll
    for (int k = 0; k < 13; ++k) {
        int yy = cy + dy[k];
        int xx = cx + dx[k];
        if (yy >= 0 && yy < H && xx >= 0 && xx < W) {
            unsigned int idx = base + (unsigned int)yy * W + (unsigned int)xx;
            atomicOr(&mask[idx >> 5], 1u << (idx & 31));
        }
    }
}

__device__ inline float wave_reduce(float v) {
#pragma unroll
    for (int o = 32; o > 0; o >>= 1) v += __shfl_down(v, o, 64);
    return v;
}

__global__ __launch_bounds__(THREADS)
void mainpass_kernel(const float* __restrict__ logits,
                     const unsigned int* __restrict__ mask,
                     float* __restrict__ part) {
    const int blk = blockIdx.x;
    const int b = blk / BLOCKS_PER_BATCH;
    const int chunk = blk % BLOCKS_PER_BATCH;
    const int base_v = b * (HW / 4) + chunk * (UNROLL * THREADS);
    const int tid = threadIdx.x;

    const f32x4* __restrict__ vlog = reinterpret_cast<const f32x4*>(logits);

    f32x4 xv[UNROLL];
    unsigned int mw[UNROLL];
#pragma unroll
    for (int it = 0; it < UNROLL; ++it) {
        int v = base_v + it * THREADS + tid;
        xv[it] = vlog[v];
        mw[it] = mask[(unsigned int)v >> 3];
    }

    float sA = 0.f, sBg = 0.f, sCg = 0.f, si = 0.f, spr = 0.f, sg = 0.f;

#pragma unroll
    for (int it = 0; it < UNROLL; ++it) {
        int v = base_v + it * THREADS + tid;
        unsigned int bits = mw[it] >> ((v & 7) * 4);   // low 4 bits valid
#pragma unroll
        for (int j = 0; j < 4; ++j) {
            float x = xv[it][j];
            float g = (float)((bits >> j) & 1u);
            float ax = fabsf(x);
            float t = __builtin_amdgcn_exp2f(-1.44269504f * ax);  // e^-|x|
            float u = 1.0f + t;
            float l = __builtin_amdgcn_logf(u) * 0.69314718f;     // log(1+t)
            float sp = l + fmaxf(x, 0.f);                         // softplus(x)
            float r = __builtin_amdgcn_rcpf(u);
            float prob = r * ((x >= 0.f) ? 1.0f : t);             // sigmoid(x)
            sA += sp;
            sBg += g * sp;
            sCg += g * x;
            si += g * prob;
            spr += prob;
            sg += g;
        }
    }

    __shared__ float red[4][6];
    int lane = threadIdx.x & 63;
    int wv = threadIdx.x >> 6;
    sA = wave_reduce(sA);
    sBg = wave_reduce(sBg);
    sCg = wave_reduce(sCg);
    si = wave_reduce(si);
    spr = wave_reduce(spr);
    sg = wave_reduce(sg);
    if (lane == 0) {
        red[wv][0] = sA; red[wv][1] = sBg; red[wv][2] = sCg;
        red[wv][3] = si; red[wv][4] = spr; red[wv][5] = sg;
    }
    __syncthreads();
    if (threadIdx.x == 0) {
        float a[6] = {0, 0, 0, 0, 0, 0};
#pragma unroll
        for (int w = 0; w < 4; ++w)
#pragma unroll
            for (int q = 0; q < 6; ++q) a[q] += red[w][q];
        // Contention-free per-block partial stores (no atomics anywhere).
#pragma unroll
        for (int q = 0; q < 6; ++q) part[q * NBLOCKS + blk] = a[q];
    }
}

__global__ __launch_bounds__(256)
void reduce_finalize_kernel(const float* __restrict__ part,
                            float* __restrict__ out) {
    const int tid = threadIdx.x;
    const int lane = tid & 63;
    const int wv = tid >> 6;

    // ---- global sums (q = 0,1,2) ----
    float a0 = 0.f, a1 = 0.f, a2 = 0.f;
#pragma unroll
    for (int k = 0; k < NBLOCKS / 256; ++k) {
        int i = tid + 256 * k;
        a0 += part[0 * NBLOCKS + i];
        a1 += part[1 * NBLOCKS + i];
        a2 += part[2 * NBLOCKS + i];
    }
    a0 = wave_reduce(a0);
    a1 = wave_reduce(a1);
    a2 = wave_reduce(a2);
    __shared__ float redg[4][3];
    if (lane == 0) { redg[wv][0] = a0; redg[wv][1] = a1; redg[wv][2] = a2; }

    // ---- per-batch sums (q = 3,4,5): 16 threads per batch ----
    int b = tid >> 4;        // 0..15
    int j = tid & 15;        // 0..15
    float p3 = 0.f, p4 = 0.f, p5 = 0.f;
#pragma unroll
    for (int k = 0; k < BLOCKS_PER_BATCH / 16; ++k) {
        int idx = b * BLOCKS_PER_BATCH + j + 16 * k;
        p3 += part[3 * NBLOCKS + idx];
        p4 += part[4 * NBLOCKS + idx];
        p5 += part[5 * NBLOCKS + idx];
    }
#pragma unroll
    for (int m = 1; m < 16; m <<= 1) {
        p3 += __shfl_xor(p3, m, 64);
        p4 += __shfl_xor(p4, m, 64);
        p5 += __shfl_xor(p5, m, 64);
    }
    __shared__ float sI[16], sP[16], sG[16];
    if (j == 0) { sI[b] = p3; sP[b] = p4; sG[b] = p5; }
    __syncthreads();

    if (tid == 0) {
        float A = 0.f, Bg = 0.f, Cg = 0.f;
#pragma unroll
        for (int w = 0; w < 4; ++w) {
            A += redg[w][0]; Bg += redg[w][1]; Cg += redg[w][2];
        }
        float S1 = Bg - Cg;          // sum g*softplus(-x)
        float S2 = A - Bg;           // sum (1-g)*softplus(x)
        float pos = 0.f;
#pragma unroll
        for (int bb = 0; bb < B; ++bb) pos += sG[bb];
        float neg = (float)TOT - pos;
        float pw = neg / (pos + SMOOTH);
        float bce = (pw * S1 + S2) / (float)TOT;
        float dsum = 0.f;
#pragma unroll
        for (int bb = 0; bb < B; ++bb) {
            dsum += (2.f * sI[bb] + SMOOTH) / (sP[bb] + sG[bb] + SMOOTH);
        }
        float dice = 1.f - dsum / (float)B;
        out[0] = 0.5f * bce + 0.5f * dice;
    }
}

extern "C" void kernel_launch(void* const* d_in, const int* in_sizes, int n_in,
                              void* d_out, int out_size, void* d_ws, size_t ws_size,
                              hipStream_t stream) {
    const float* logits = (const float*)d_in[0];
    const int* pts = (const int*)d_in[1];
    unsigned int* mask = (unsigned int*)d_ws;
    float* part = (float*)((char*)d_ws + MASK_BYTES);

    // Custom wide zero of the mask (no hipMemsetAsync / rocclr fill).
    zero_kernel<<<(int)(MASK_WORDS / 4 / 256), 256, 0, stream>>>(
        reinterpret_cast<u32x4*>(mask));

    raster_kernel<<<(B * N + 255) / 256, 256, 0, stream>>>(pts, mask);

    mainpass_kernel<<<NBLOCKS, THREADS, 0, stream>>>(logits, mask, part);

    reduce_finalize_kernel<<<1, 256, 0, stream>>>(part, (float*)d_out);
}